// Round 6
// baseline (145.883 us; speedup 1.0000x reference)
//
#include <hip/hip_runtime.h>
#include <math.h>

// Problem constants (B, NP, NQ, D) = (4, 256, 256, 512)
#define BB   4
#define NP   256
#define NQ   256
#define DD   512
#define DD4  (DD / 4)

typedef float f32x4 __attribute__((ext_vector_type(4)));

static constexpr float kScale = 1.0f / 22.627417f;  // 1/sqrt(512)

// ---------------------------------------------------------------------------
// Launch 1: gate kernel. 4 softmax rows per block over q_scores = qq.qk^T/T.
// Gates are NOT an output; scatter each gate[b,n,p] into the private slot of
// the store block that will consume it: slot(b, n>>3, p>>5) = the first 256
// floats of out[b, (n>>3)*8, (p>>5)*32, :], at offset (n&7)*32 + (p&31).
// Every slot lies inside its owner store-block's own output region, so the
// stash is overwritten only by the block that already read it. Grid (64, 4).
// ---------------------------------------------------------------------------
__global__ __launch_bounds__(256) void gate_kernel(
    const float* __restrict__ qq,    // [B, NQ, D]
    const float* __restrict__ qk,    // [B, NP, D]
    float* __restrict__ outf)        // [B, NQ, NP, D]
{
    const int b  = blockIdx.y;
    const int n0 = blockIdx.x * 4;
    const int t  = threadIdx.x;

    const f32x4* krow = (const f32x4*)(qk + ((size_t)b * NP + t) * DD);
    const float* qb   = qq + ((size_t)b * NQ + n0) * DD;   // wave-uniform

    float acc[4] = {0.f, 0.f, 0.f, 0.f};
    #pragma unroll 8
    for (int d4 = 0; d4 < DD4; ++d4) {
        const f32x4 kv = krow[d4];
        #pragma unroll
        for (int r = 0; r < 4; ++r) {
            const float* qr = qb + r * DD + d4 * 4;
            acc[r] += qr[0] * kv.x + qr[1] * kv.y + qr[2] * kv.z + qr[3] * kv.w;
        }
    }

    __shared__ __align__(16) float ss[4][256];
    #pragma unroll
    for (int r = 0; r < 4; ++r) ss[r][t] = acc[r] * kScale;
    __syncthreads();

    // Wave r reduces row n0+r; lane g owns cols 4g..4g+3.
    const int r = t >> 6;
    const int g = t & 63;
    const f32x4 sv = ((const f32x4*)ss[r])[g];

    float m = fmaxf(fmaxf(sv.x, sv.y), fmaxf(sv.z, sv.w));
    #pragma unroll
    for (int off = 32; off >= 1; off >>= 1) m = fmaxf(m, __shfl_xor(m, off, 64));

    f32x4 ev;
    ev.x = expf(sv.x - m); ev.y = expf(sv.y - m);
    ev.z = expf(sv.z - m); ev.w = expf(sv.w - m);
    float s = (ev.x + ev.y) + (ev.z + ev.w);
    #pragma unroll
    for (int off = 32; off >= 1; off >>= 1) s += __shfl_xor(s, off, 64);
    const float inv = 1.0f / s;

    // Scatter into the consumer store-block's slot.
    const int n  = n0 + r;
    const int ng = n >> 3, nr = n & 7;
    const int c0 = 4 * g;            // first of 4 consecutive p-columns
    const int pr = c0 >> 5;
    float* slot = outf
        + (((size_t)(b * NQ + (ng << 3))) * NP + (pr << 5)) * DD
        + nr * 32 + (c0 & 31);
    *(f32x4*)slot = ev * inv;        // 16B-aligned
}

// ---------------------------------------------------------------------------
// Launch 2, grid.x = 1280:
//  blocks [0,1024):   store machine. Block owns (b, 8 n-rows, 32 p-cols).
//                     Reads its 256 stashed gates -> LDS, then streams
//                     out[b,n0+r,p,:] = gate * (v[b,p,:] + qv[b,n0+r,:]),
//                     one v load per 8 stores, qv in 8 registers.
//  blocks [1024,1280): attn/log_attn = softmax(q.k^T/T), 4 rows each.
// ---------------------------------------------------------------------------
__global__ __launch_bounds__(256) void store_kernel(
    const float* __restrict__ q,     // [B, NP, D]
    const float* __restrict__ k,     // [B, NP, D]
    const f32x4* __restrict__ v4,    // [B, NP, DD4]
    const f32x4* __restrict__ qv4,   // [B, NQ, DD4]
    float* __restrict__ outf,        // [B, NQ, NP, D]
    float* __restrict__ attn_out,    // [B, NP, NP]
    float* __restrict__ logattn_out) // [B, NP, NP]
{
    __shared__ __align__(16) float smem[4 * 256];
    const int t = threadIdx.x;

    if (blockIdx.x < 1024u) {
        // ---------------- type A: pure streaming write ----------------
        const int idx  = blockIdx.x;
        const int b    = idx >> 8;
        const int rest = idx & 255;
        const int n0   = (rest >> 3) << 3;   // 0,8,...,248
        const int p0   = (rest & 7) << 5;    // 0,32,...,224

        // Gates for this tile were stashed at the head of our own region.
        const float* slot = outf + (((size_t)(b * NQ + n0)) * NP + p0) * DD;
        smem[t] = slot[t];
        __syncthreads();

        const int d4 = t & (DD4 - 1);
        const int po = t >> 7;               // 0 or 1
        const f32x4* qvb = qv4 + ((size_t)(b * NQ + n0)) * DD4 + d4;
        f32x4 qvr[8];
        #pragma unroll
        for (int r = 0; r < 8; ++r) qvr[r] = qvb[(size_t)r * DD4];

        const f32x4* vcol  = v4 + ((size_t)b * NP) * DD4 + d4;
        f32x4*       obase = (f32x4*)outf + (((size_t)(b * NQ + n0)) * NP) * DD4 + d4;

        #pragma unroll 2
        for (int pi = 0; pi < 16; ++pi) {
            const int p  = p0 + 2 * pi + po;
            const int pc = 2 * pi + po;      // wave-uniform gate column
            const f32x4 vv = vcol[(size_t)p * DD4];
            #pragma unroll
            for (int r = 0; r < 8; ++r) {
                const float gpn = smem[r * 32 + pc];   // LDS broadcast
                __builtin_nontemporal_store((vv + qvr[r]) * gpn,
                    obase + ((size_t)r * NP + p) * DD4);
            }
        }
    } else {
        // ---------------- type B: attn / log_attn softmax ----------------
        const int idx = blockIdx.x - 1024;   // 0..255
        const int b   = idx >> 6;
        const int p0  = (idx & 63) * 4;

        const f32x4* krow = (const f32x4*)(k + ((size_t)b * NP + t) * DD);
        const float* qb   = q + ((size_t)b * NP + p0) * DD;   // wave-uniform

        float acc[4] = {0.f, 0.f, 0.f, 0.f};
        #pragma unroll 8
        for (int d4 = 0; d4 < DD4; ++d4) {
            const f32x4 kv = krow[d4];
            #pragma unroll
            for (int r = 0; r < 4; ++r) {
                const float* qr = qb + r * DD + d4 * 4;
                acc[r] += qr[0] * kv.x + qr[1] * kv.y + qr[2] * kv.z + qr[3] * kv.w;
            }
        }

        float (*ss)[256] = (float (*)[256])smem;
        #pragma unroll
        for (int r = 0; r < 4; ++r) ss[r][t] = acc[r] * kScale;
        __syncthreads();

        const int r = t >> 6;
        const int g = t & 63;
        const f32x4 sv = ((const f32x4*)ss[r])[g];

        float m = fmaxf(fmaxf(sv.x, sv.y), fmaxf(sv.z, sv.w));
        #pragma unroll
        for (int off = 32; off >= 1; off >>= 1)
            m = fmaxf(m, __shfl_xor(m, off, 64));

        f32x4 ev;
        ev.x = expf(sv.x - m); ev.y = expf(sv.y - m);
        ev.z = expf(sv.z - m); ev.w = expf(sv.w - m);
        float s = (ev.x + ev.y) + (ev.z + ev.w);
        #pragma unroll
        for (int off = 32; off >= 1; off >>= 1) s += __shfl_xor(s, off, 64);

        const float inv = 1.0f / s;
        const float lse = logf(s);

        const size_t base = ((size_t)b * NP + (p0 + r)) * 256;
        ((f32x4*)(attn_out + base))[g] = ev * inv;
        f32x4 lg;
        lg.x = (sv.x - m) - lse; lg.y = (sv.y - m) - lse;
        lg.z = (sv.z - m) - lse; lg.w = (sv.w - m) - lse;
        ((f32x4*)(logattn_out + base))[g] = lg;
    }
}

extern "C" void kernel_launch(void* const* d_in, const int* in_sizes, int n_in,
                              void* d_out, int out_size, void* d_ws, size_t ws_size,
                              hipStream_t stream) {
    // setup_inputs order: q, k, v, query(unused), query_q, query_k, query_v
    const float* q  = (const float*)d_in[0];
    const float* k  = (const float*)d_in[1];
    const float* v  = (const float*)d_in[2];
    const float* qq = (const float*)d_in[4];
    const float* qk = (const float*)d_in[5];
    const float* qv = (const float*)d_in[6];

    float* out = (float*)d_out;
    const size_t out_elems = (size_t)BB * NQ * NP * DD;          // 134,217,728
    float* attn_out    = out + out_elems;                         // [B,NP,256]
    float* logattn_out = attn_out + (size_t)BB * NP * 256;        // [B,NP,256]

    // 1) gates -> per-store-block slots inside out.
    gate_kernel<<<dim3(NQ / 4, BB), 256, 0, stream>>>(qq, qk, out);

    // 2) streaming gated-combine write + (hidden) attn/log_attn softmax.
    store_kernel<<<1280, 256, 0, stream>>>(
        q, k, (const f32x4*)v, (const f32x4*)qv, out, attn_out, logattn_out);
}